// Round 5
// baseline (104.575 us; speedup 1.0000x reference)
//
#include <hip/hip_runtime.h>
#include <math.h>

#define TS 8192               // dg table size (32 KB, L1/L2-resident)
#define NPTS 16384            // N per row
#define NROWS 256             // B
#define CPR 8                 // chunks per row
#define CHUNK 2048            // elements per chunk
#define EPT 8                 // elements per thread (256 thr * 8 = 2048)

// softplus via hardware transcendentals (v_exp_f32 / v_log_f32)
__device__ __forceinline__ float softplus(float x) {
    float ax = fabsf(x);
    return fmaxf(x, 0.0f) + __logf(1.0f + __expf(-ax));
}

// LDS layout offsets (floats) for the staged weights
#define OFF_W1 0            // 32
#define OFF_B1 32           // 32
#define OFF_W2 64           // 2048
#define OFF_B2 2112         // 64
#define OFF_W3 2176         // 4096
#define OFF_B3 6272         // 64
#define OFF_W4 6336         // 2048
#define OFF_B4 8384         // 32
#define OFF_W5 8416         // 32
#define OFF_B5 8448         // 1
#define WTOT   8449

// Kernel 1: tabulate dg(t) = MLP(t) on uniform grid over [0,10].
// (R4 structure, measured <45us, est ~5us: block=512 computes 32 entries;
// lane&31 = entry, lane>>5 = k-half, wave = j-slice; weights in LDS,
// layer exchange via padded hbuf, halves combined via shfl_xor(32).)
__global__ __launch_bounds__(512, 2) void build_table(
    const float* __restrict__ W1, const float* __restrict__ b1,
    const float* __restrict__ W2, const float* __restrict__ b2,
    const float* __restrict__ W3, const float* __restrict__ b3,
    const float* __restrict__ W4, const float* __restrict__ b4,
    const float* __restrict__ W5, const float* __restrict__ b5,
    float* __restrict__ table)
{
    __shared__ float w[WTOT];
    __shared__ float hbuf[32][65];

    const int tid  = threadIdx.x;
    const int lane = tid & 63;
    const int wave = tid >> 6;
    const int half = lane >> 5;
    const int e    = lane & 31;

    {
        float4*       d2 = (float4*)(w + OFF_W2);
        const float4* s2 = (const float4*)W2;
        d2[tid] = s2[tid];
        float4*       d3 = (float4*)(w + OFF_W3);
        const float4* s3 = (const float4*)W3;
        d3[tid] = s3[tid]; d3[512 + tid] = s3[512 + tid];
        float4*       d4 = (float4*)(w + OFF_W4);
        const float4* s4 = (const float4*)W4;
        d4[tid] = s4[tid];
        if (tid < 32) {
            w[OFF_W1 + tid] = W1[tid];
            w[OFF_B1 + tid] = b1[tid];
            w[OFF_B4 + tid] = b4[tid];
            w[OFF_W5 + tid] = W5[tid];
        }
        if (tid < 64) {
            w[OFF_B2 + tid] = b2[tid];
            w[OFF_B3 + tid] = b3[tid];
        }
        if (tid == 0) w[OFF_B5] = b5[0];
    }
    __syncthreads();

    const int   i = blockIdx.x * 32 + e;
    const float t = 10.0f * (float)i / (float)(TS - 1);

    // L1: 1 -> 32
#pragma unroll
    for (int jj = 0; jj < 4; ++jj) {
        int j = wave * 4 + jj;
        float v = softplus(fmaf(t, w[OFF_W1 + j], w[OFF_B1 + j]));
        if (half == 0) hbuf[e][j] = v;
    }
    __syncthreads();

    // L2: 32 -> 64
    {
        float hr[16];
        const float* hp = &hbuf[e][half * 16];
#pragma unroll
        for (int k = 0; k < 16; ++k) hr[k] = hp[k];
        float acc[8];
#pragma unroll
        for (int jj = 0; jj < 8; ++jj) {
            int j = wave * 8 + jj;
            const float* wp = &w[OFF_W2 + j * 32 + half * 16];
            float a = 0.0f;
#pragma unroll
            for (int k = 0; k < 16; ++k) a = fmaf(hr[k], wp[k], a);
            acc[jj] = a;
        }
        __syncthreads();
#pragma unroll
        for (int jj = 0; jj < 8; ++jj) {
            int j = wave * 8 + jj;
            float s = acc[jj] + __shfl_xor(acc[jj], 32, 64);
            float v = softplus(s + w[OFF_B2 + j]);
            if (half == 0) hbuf[e][j] = v;
        }
    }
    __syncthreads();

    // L3: 64 -> 64
    {
        float hr[32];
        const float* hp = &hbuf[e][half * 32];
#pragma unroll
        for (int k = 0; k < 32; ++k) hr[k] = hp[k];
        float acc[8];
#pragma unroll
        for (int jj = 0; jj < 8; ++jj) {
            int j = wave * 8 + jj;
            const float* wp = &w[OFF_W3 + j * 64 + half * 32];
            float a = 0.0f;
#pragma unroll
            for (int k = 0; k < 32; ++k) a = fmaf(hr[k], wp[k], a);
            acc[jj] = a;
        }
        __syncthreads();
#pragma unroll
        for (int jj = 0; jj < 8; ++jj) {
            int j = wave * 8 + jj;
            float s = acc[jj] + __shfl_xor(acc[jj], 32, 64);
            float v = softplus(s + w[OFF_B3 + j]);
            if (half == 0) hbuf[e][j] = v;
        }
    }
    __syncthreads();

    // L4: 64 -> 32
    {
        float hr[32];
        const float* hp = &hbuf[e][half * 32];
#pragma unroll
        for (int k = 0; k < 32; ++k) hr[k] = hp[k];
        float acc[4];
#pragma unroll
        for (int jj = 0; jj < 4; ++jj) {
            int j = wave * 4 + jj;
            const float* wp = &w[OFF_W4 + j * 64 + half * 32];
            float a = 0.0f;
#pragma unroll
            for (int k = 0; k < 32; ++k) a = fmaf(hr[k], wp[k], a);
            acc[jj] = a;
        }
        __syncthreads();
#pragma unroll
        for (int jj = 0; jj < 4; ++jj) {
            int j = wave * 4 + jj;
            float s = acc[jj] + __shfl_xor(acc[jj], 32, 64);
            float v = softplus(s + w[OFF_B4 + j]);
            if (half == 0) hbuf[e][j] = v;
        }
    }
    __syncthreads();

    // L5: 32 -> 1, +1.0
    if (wave == 0) {
        const float* hp = &hbuf[e][half * 16];
        const float* wp = &w[OFF_W5 + half * 16];
        float a = 0.0f;
#pragma unroll
        for (int k = 0; k < 16; ++k) a = fmaf(hp[k], wp[k], a);
        float s = a + __shfl_xor(a, 32, 64);
        float v = softplus(s + w[OFF_B5]) + 1.0f;
        if (half == 0) table[blockIdx.x * 32 + e] = v;
    }
}

__device__ __forceinline__ float dg_lookup(const float* __restrict__ tab, float t) {
    const float scale = (float)(TS - 1) / 10.0f;
    float x = t * scale;
    x = fminf(fmaxf(x, 0.0f), (float)(TS - 1));
    int i = (int)x;
    if (i > TS - 2) i = TS - 2;
    float f = x - (float)i;
    float a = tab[i];
    float b = tab[i + 1];
    return fmaf(b - a, f, a);
}

// Shared helper: load 8 t's + tprev, compute 8 trapezoid increments.
// Returns per-thread sum; inc[] filled. Table gathered via L1/L2 (32 KB,
// cache-resident -- R0 vs R2 showed LDS staging buys nothing).
__device__ __forceinline__ float chunk_increments(
    const float* __restrict__ tr, const float* __restrict__ table,
    int base, float inc[EPT])
{
    float tv[EPT];
    const float4* p = (const float4*)(tr + base);
    float4 a = p[0], b = p[1];
    tv[0] = a.x; tv[1] = a.y; tv[2] = a.z; tv[3] = a.w;
    tv[4] = b.x; tv[5] = b.y; tv[6] = b.z; tv[7] = b.w;

    // neighbor handoff: lane i gets lane i-1's tv[7]; lane 0 loads directly
    float tprev = __shfl_up(tv[7], 1, 64);
    if ((threadIdx.x & 63) == 0)
        tprev = (base == 0) ? tv[0] : tr[base - 1];

    float s  = 0.0f;
    float tp = tprev;
    float dp = dg_lookup(table, tprev);
#pragma unroll
    for (int q = 0; q < EPT; ++q) {
        float dc = dg_lookup(table, tv[q]);
        inc[q] = 0.5f * (dc + dp) * (tv[q] - tp);
        s += inc[q];
        tp = tv[q];
        dp = dc;
    }
    return s;
}

// K0: per-chunk trapezoid totals. 2048 blocks x 256 threads.
__global__ __launch_bounds__(256) void chunk_sums(
    const float* __restrict__ t,
    const float* __restrict__ table,
    float* __restrict__ sums)
{
    const int blk   = blockIdx.x;          // 0..2047
    const int row   = blk >> 3;
    const int chunk = blk & (CPR - 1);
    const float* tr = t + (size_t)row * NPTS;
    const int tid   = threadIdx.x;
    const int base  = chunk * CHUNK + tid * EPT;

    float inc[EPT];
    float s = chunk_increments(tr, table, base, inc);

    // wave reduce + 4-wave LDS combine
    float v = s;
#pragma unroll
    for (int d = 1; d < 64; d <<= 1) v += __shfl_xor(v, d, 64);
    __shared__ float ws4[4];
    if ((tid & 63) == 0) ws4[tid >> 6] = v;
    __syncthreads();
    if (tid == 0) sums[blk] = ws4[0] + ws4[1] + ws4[2] + ws4[3];
}

// K2: final scan+emit. 2048 blocks x 256 threads.
__global__ __launch_bounds__(256) void integrate2(
    const float* __restrict__ t,
    const float* __restrict__ table,
    const float* __restrict__ sums,
    float* __restrict__ out)
{
    const int blk   = blockIdx.x;
    const int row   = blk >> 3;
    const int chunk = blk & (CPR - 1);
    const float* tr = t + (size_t)row * NPTS;
    float*       gr = out + (size_t)row * NPTS;
    const int tid   = threadIdx.x;
    const int base  = chunk * CHUNK + tid * EPT;

    float inc[EPT];
    float s = chunk_increments(tr, table, base, inc);

    // offset from preceding chunks of this row (wave-uniform scalar loads)
    float off = 0.0f;
#pragma unroll
    for (int j = 0; j < CPR - 1; ++j)
        if (j < chunk) off += sums[row * CPR + j];

    // wave-level inclusive scan of per-thread totals
    const int lane = tid & 63;
    const int wave = tid >> 6;
    float v = s;
#pragma unroll
    for (int d = 1; d < 64; d <<= 1) {
        float u = __shfl_up(v, d, 64);
        if (lane >= d) v += u;
    }
    __shared__ float wsum[4];
    if (lane == 63) wsum[wave] = v;
    __syncthreads();
    float woff = 0.0f;
#pragma unroll
    for (int w = 0; w < 4; ++w)
        woff += (w < wave) ? wsum[w] : 0.0f;

    float running = off + woff + (v - s);   // exclusive prefix
    float4* g4 = (float4*)(gr + base);
    float4 o0, o1;
    running += inc[0]; o0.x = running;
    running += inc[1]; o0.y = running;
    running += inc[2]; o0.z = running;
    running += inc[3]; o0.w = running;
    running += inc[4]; o1.x = running;
    running += inc[5]; o1.y = running;
    running += inc[6]; o1.z = running;
    running += inc[7]; o1.w = running;
    g4[0] = o0; g4[1] = o1;
}

extern "C" void kernel_launch(void* const* d_in, const int* in_sizes, int n_in,
                              void* d_out, int out_size, void* d_ws, size_t ws_size,
                              hipStream_t stream)
{
    const float* t  = (const float*)d_in[0];
    const float* W1 = (const float*)d_in[1];
    const float* b1 = (const float*)d_in[2];
    const float* W2 = (const float*)d_in[3];
    const float* b2 = (const float*)d_in[4];
    const float* W3 = (const float*)d_in[5];
    const float* b3 = (const float*)d_in[6];
    const float* W4 = (const float*)d_in[7];
    const float* b4 = (const float*)d_in[8];
    const float* W5 = (const float*)d_in[9];
    const float* b5 = (const float*)d_in[10];
    float* table = (float*)d_ws;                       // 32 KB
    float* sums  = (float*)d_ws + 16384;               // 2048 floats @ +64 KB
    float* out   = (float*)d_out;

    build_table<<<TS / 32, 512, 0, stream>>>(W1, b1, W2, b2, W3, b3, W4, b4, W5, b5, table);
    chunk_sums<<<NROWS * CPR, 256, 0, stream>>>(t, table, sums);
    integrate2<<<NROWS * CPR, 256, 0, stream>>>(t, table, sums, out);
}